// Round 1
// baseline (1649.252 us; speedup 1.0000x reference)
//
#include <hip/hip_runtime.h>

#define NN 50000
#define NE 600000
#define DD 128
#define RR 8
#define NBASIS 4
#define NR (NN * RR)

// ---------------------------------------------------------------------------
// W[k*1024 + r*128 + o] = sum_b comp[r,b] * basis[b,k,o]   (k-major, 128x1024)
__global__ __launch_bounds__(256) void build_w_kernel(
    const float* __restrict__ basis, const float* __restrict__ comp,
    float* __restrict__ W) {
  int idx = blockIdx.x * 256 + threadIdx.x;
  if (idx >= DD * RR * DD) return;
  int k = idx >> 10;        // / (RR*DD)
  int rem = idx & 1023;
  int r = rem >> 7;
  int o = rem & 127;
  float acc = 0.f;
#pragma unroll
  for (int b = 0; b < NBASIS; ++b)
    acc += comp[r * NBASIS + b] * basis[((size_t)b * DD + k) * DD + o];
  W[idx] = acc;
}

// ---------------------------------------------------------------------------
__global__ __launch_bounds__(256) void count_edges_kernel(
    const int* __restrict__ dst, const int* __restrict__ et,
    int* __restrict__ cnt) {
  int e = blockIdx.x * 256 + threadIdx.x;
  if (e < NE) atomicAdd(&cnt[dst[e] * RR + et[e]], 1);
}

__global__ __launch_bounds__(256) void make_inv_kernel(
    const int* __restrict__ cnt, float* __restrict__ inv) {
  int i = blockIdx.x * 256 + threadIdx.x;
  if (i < NR) inv[i] = 1.0f / (float)max(cnt[i], 1);
}

// ---------------------------------------------------------------------------
// C[M, ncols] = A[M,128] @ B[128, ncols] (+ bias).  64x64 tile, 256 threads,
// each thread 4x4 outputs.  K=128 staged fully in LDS.
__global__ __launch_bounds__(256) void gemm_k128(
    const float* __restrict__ A, const float* __restrict__ B,
    const float* __restrict__ bias, float* __restrict__ C, int M, int ncols) {
  __shared__ float As[128][68];  // As[k][row], pad 68 keeps float4 alignment
  __shared__ float Bs[128][68];  // Bs[k][col]

  int row0 = blockIdx.x * 64;
  int col0 = blockIdx.y * 64;
  int tid = threadIdx.x;

  // A tile: 64 rows x 128 k  (transpose into As[k][row])
  for (int l = tid; l < 64 * 32; l += 256) {
    int r = l >> 5;
    int k4 = (l & 31) << 2;
    int grow = row0 + r;
    float4 v = make_float4(0.f, 0.f, 0.f, 0.f);
    if (grow < M) v = *(const float4*)(A + (size_t)grow * 128 + k4);
    As[k4 + 0][r] = v.x;
    As[k4 + 1][r] = v.y;
    As[k4 + 2][r] = v.z;
    As[k4 + 3][r] = v.w;
  }
  // B tile: 128 k x 64 cols
  for (int l = tid; l < 128 * 16; l += 256) {
    int k = l >> 4;
    int c4 = (l & 15) << 2;
    float4 v = *(const float4*)(B + (size_t)k * ncols + col0 + c4);
    *(float4*)&Bs[k][c4] = v;
  }
  __syncthreads();

  int tx = tid & 15;   // col group
  int ty = tid >> 4;   // row group
  float acc[4][4] = {};
#pragma unroll 8
  for (int k = 0; k < 128; ++k) {
    float4 a = *(const float4*)&As[k][ty * 4];
    float4 b = *(const float4*)&Bs[k][tx * 4];
    float av[4] = {a.x, a.y, a.z, a.w};
    float bv[4] = {b.x, b.y, b.z, b.w};
#pragma unroll
    for (int i = 0; i < 4; ++i)
#pragma unroll
      for (int j = 0; j < 4; ++j) acc[i][j] += av[i] * bv[j];
  }

  float4 bb = make_float4(0.f, 0.f, 0.f, 0.f);
  if (bias) bb = *(const float4*)(bias + col0 + tx * 4);

#pragma unroll
  for (int i = 0; i < 4; ++i) {
    int grow = row0 + ty * 4 + i;
    if (grow < M) {
      float4 o;
      o.x = acc[i][0] + bb.x;
      o.y = acc[i][1] + bb.y;
      o.z = acc[i][2] + bb.z;
      o.w = acc[i][3] + bb.w;
      *(float4*)(C + (size_t)grow * ncols + col0 + tx * 4) = o;
    }
  }
}

// ---------------------------------------------------------------------------
// One 64-lane wave per edge: out[dst] += inv[dst*R+t] * xw[src*R+t]
__global__ __launch_bounds__(256) void scatter_edges_kernel(
    const float* __restrict__ xw, const int* __restrict__ src,
    const int* __restrict__ dst, const int* __restrict__ et,
    const float* __restrict__ inv, float* __restrict__ outp) {
  long long gid = (long long)blockIdx.x * 256 + threadIdx.x;
  int e = (int)(gid >> 6);
  int lane = (int)(gid & 63);
  if (e >= NE) return;
  int s = src[e];
  int d = dst[e];
  int t = et[e];
  float scale = inv[d * RR + t];
  const float2* row = (const float2*)(xw + ((size_t)s * RR + t) * DD);
  float2 v = row[lane];
  float* orow = outp + (size_t)d * DD + lane * 2;
  atomicAdd(orow + 0, scale * v.x);
  atomicAdd(orow + 1, scale * v.y);
}

// ---------------------------------------------------------------------------
__global__ __launch_bounds__(256) void relu_kernel(float* __restrict__ h, int n) {
  int i = blockIdx.x * 256 + threadIdx.x;
  if (i < n) h[i] = fmaxf(h[i], 0.f);
}

// ---------------------------------------------------------------------------
extern "C" void kernel_launch(void* const* d_in, const int* in_sizes, int n_in,
                              void* d_out, int out_size, void* d_ws,
                              size_t ws_size, hipStream_t stream) {
  const float* x      = (const float*)d_in[0];
  const int*   eidx   = (const int*)d_in[1];
  const int*   etype  = (const int*)d_in[2];
  const float* basis1 = (const float*)d_in[3];
  const float* comp1  = (const float*)d_in[4];
  const float* root1  = (const float*)d_in[5];
  const float* bias1  = (const float*)d_in[6];
  const float* basis2 = (const float*)d_in[7];
  const float* comp2  = (const float*)d_in[8];
  const float* root2  = (const float*)d_in[9];
  const float* bias2  = (const float*)d_in[10];
  float* out = (float*)d_out;

  const int* src = eidx;
  const int* dst = eidx + NE;

  // workspace layout (floats):
  //   W1 131072 | W2 131072 | inv 400000 | cnt 400000(int) | h 6.4M | xw 51.2M
  float* W1  = (float*)d_ws;
  float* W2  = W1 + 131072;
  float* inv = W2 + 131072;
  int*   cnt = (int*)(inv + NR);
  float* h   = (float*)(cnt + NR);
  float* xw  = h + (size_t)NN * DD;

  hipMemsetAsync(cnt, 0, NR * sizeof(int), stream);
  count_edges_kernel<<<(NE + 255) / 256, 256, 0, stream>>>(dst, etype, cnt);
  make_inv_kernel<<<(NR + 255) / 256, 256, 0, stream>>>(cnt, inv);

  build_w_kernel<<<(DD * RR * DD + 255) / 256, 256, 0, stream>>>(basis1, comp1, W1);
  build_w_kernel<<<(DD * RR * DD + 255) / 256, 256, 0, stream>>>(basis2, comp2, W2);

  dim3 gxw((NN + 63) / 64, (RR * DD) / 64);  // 782 x 16
  dim3 groot((NN + 63) / 64, DD / 64);       // 782 x 2
  int scatter_blocks = (int)(((long long)NE * 64 + 255) / 256);

  // ---- layer 1 ----
  gemm_k128<<<gxw, 256, 0, stream>>>(x, W1, nullptr, xw, NN, RR * DD);
  gemm_k128<<<groot, 256, 0, stream>>>(x, root1, bias1, h, NN, DD);
  scatter_edges_kernel<<<scatter_blocks, 256, 0, stream>>>(xw, src, dst, etype, inv, h);
  relu_kernel<<<(NN * DD + 255) / 256, 256, 0, stream>>>(h, NN * DD);

  // ---- layer 2 ----
  gemm_k128<<<gxw, 256, 0, stream>>>(h, W2, nullptr, xw, NN, RR * DD);
  gemm_k128<<<groot, 256, 0, stream>>>(h, root2, bias2, out, NN, DD);
  scatter_edges_kernel<<<scatter_blocks, 256, 0, stream>>>(xw, src, dst, etype, inv, out);
}

// Round 2
// 613.877 us; speedup vs baseline: 2.6866x; 2.6866x over previous
//
#include <hip/hip_runtime.h>

#define NN 50000
#define NE 600000
#define DD 128
#define RR 8
#define NBASIS 4
#define NR (NN * RR)
#define KTOT 640   // 4*128 (z) + 128 (self feat)

// ---------------------------------------------------------------------------
// Count edges per (dst, etype) and per dst.
__global__ __launch_bounds__(256) void count_kernel(
    const int* __restrict__ dst, const int* __restrict__ et,
    int* __restrict__ cnt, int* __restrict__ deg) {
  int e = blockIdx.x * 256 + threadIdx.x;
  if (e < NE) {
    int d = dst[e];
    atomicAdd(&cnt[d * RR + et[e]], 1);
    atomicAdd(&deg[d], 1);
  }
}

// ---------------------------------------------------------------------------
// 3-kernel exclusive scan of deg[NN] -> offs[NN]
__global__ __launch_bounds__(256) void scan1_kernel(
    const int* __restrict__ deg, int* __restrict__ offs,
    int* __restrict__ partials) {
  __shared__ int s[256];
  int t = threadIdx.x;
  int i = blockIdx.x * 256 + t;
  int v = (i < NN) ? deg[i] : 0;
  s[t] = v;
  __syncthreads();
  for (int off = 1; off < 256; off <<= 1) {
    int add = (t >= off) ? s[t - off] : 0;
    __syncthreads();
    s[t] += add;
    __syncthreads();
  }
  if (i < NN) offs[i] = s[t] - v;  // exclusive within block
  if (t == 255) partials[blockIdx.x] = s[255];
}

__global__ __launch_bounds__(256) void scan2_kernel(
    int* __restrict__ partials, int nb) {
  __shared__ int s[256];
  int t = threadIdx.x;
  int v = (t < nb) ? partials[t] : 0;
  s[t] = v;
  __syncthreads();
  for (int off = 1; off < 256; off <<= 1) {
    int add = (t >= off) ? s[t - off] : 0;
    __syncthreads();
    s[t] += add;
    __syncthreads();
  }
  if (t < nb) partials[t] = s[t] - v;  // exclusive
}

__global__ __launch_bounds__(256) void scan3_kernel(
    int* __restrict__ offs, const int* __restrict__ partials,
    int* __restrict__ cursor) {
  int i = blockIdx.x * 256 + threadIdx.x;
  if (i < NN) {
    int o = offs[i] + partials[blockIdx.x];
    offs[i] = o;
    cursor[i] = o;
  }
}

// ---------------------------------------------------------------------------
// Scatter edges into dst-sorted order: skey = src | (etype<<28), sinv = 1/cnt.
__global__ __launch_bounds__(256) void sort_kernel(
    const int* __restrict__ src, const int* __restrict__ dst,
    const int* __restrict__ et, const int* __restrict__ cnt,
    int* __restrict__ cursor, int* __restrict__ skey,
    float* __restrict__ sinv) {
  int e = blockIdx.x * 256 + threadIdx.x;
  if (e >= NE) return;
  int d = dst[e];
  int t = et[e];
  int p = atomicAdd(&cursor[d], 1);
  skey[p] = src[e] | (t << 28);
  sinv[p] = 1.0f / (float)cnt[d * RR + t];
}

// ---------------------------------------------------------------------------
// One wave per dst node: z[d, b, :] = sum_edges (comp[t,b]/cnt[d,t]) * feat[src]
// Writes A row d: cols [0,512) = z (4 bases x 128), cols [512,640) = feat[d].
__global__ __launch_bounds__(256) void agg_kernel(
    const float* __restrict__ feat, const int* __restrict__ skey,
    const float* __restrict__ sinv, const float* __restrict__ comp,
    const int* __restrict__ offs, const int* __restrict__ deg,
    float* __restrict__ A) {
  __shared__ float scomp[RR * NBASIS];
  if (threadIdx.x < RR * NBASIS) scomp[threadIdx.x] = comp[threadIdx.x];
  __syncthreads();

  int node = blockIdx.x * 4 + (threadIdx.x >> 6);
  if (node >= NN) return;
  int lane = threadIdx.x & 63;

  float2 z0 = {0.f, 0.f}, z1 = {0.f, 0.f}, z2 = {0.f, 0.f}, z3 = {0.f, 0.f};

  int beg = offs[node];
  int end = beg + deg[node];
  for (int i = beg; i < end; ++i) {
    int key = skey[i];
    int s = key & 0x0FFFFFFF;
    int t = key >> 28;
    float iv = sinv[i];
    float2 v = ((const float2*)(feat + (size_t)s * DD))[lane];
    float c0 = iv * scomp[t * NBASIS + 0];
    float c1 = iv * scomp[t * NBASIS + 1];
    float c2 = iv * scomp[t * NBASIS + 2];
    float c3 = iv * scomp[t * NBASIS + 3];
    z0.x += c0 * v.x; z0.y += c0 * v.y;
    z1.x += c1 * v.x; z1.y += c1 * v.y;
    z2.x += c2 * v.x; z2.y += c2 * v.y;
    z3.x += c3 * v.x; z3.y += c3 * v.y;
  }

  float* Arow = A + (size_t)node * KTOT;
  ((float2*)(Arow + 0 * DD))[lane] = z0;
  ((float2*)(Arow + 1 * DD))[lane] = z1;
  ((float2*)(Arow + 2 * DD))[lane] = z2;
  ((float2*)(Arow + 3 * DD))[lane] = z3;
  // self features into cols [512, 640)
  float2 sv = ((const float2*)(feat + (size_t)node * DD))[lane];
  ((float2*)(Arow + 4 * DD))[lane] = sv;
}

// ---------------------------------------------------------------------------
// C[M,128] = A[M,640] @ BS[640,128] + bias, optional relu.
// 64x64 tile, 256 threads, 4x4 outputs/thread, BK=128 staged in LDS.
__global__ __launch_bounds__(256) void gemm640_kernel(
    const float* __restrict__ A, const float* __restrict__ BS,
    const float* __restrict__ bias, float* __restrict__ C, int do_relu) {
  __shared__ float As[128][68];
  __shared__ float Bs[128][68];

  int row0 = blockIdx.x * 64;
  int col0 = blockIdx.y * 64;
  int tid = threadIdx.x;
  int tx = tid & 15;
  int ty = tid >> 4;

  float acc[4][4] = {};

  for (int kt = 0; kt < KTOT; kt += 128) {
    // A tile: 64 rows x 128 k (transposed into As[k][row])
    for (int l = tid; l < 64 * 32; l += 256) {
      int r = l >> 5;
      int k4 = (l & 31) << 2;
      int grow = row0 + r;
      float4 v = make_float4(0.f, 0.f, 0.f, 0.f);
      if (grow < NN) v = *(const float4*)(A + (size_t)grow * KTOT + kt + k4);
      As[k4 + 0][r] = v.x;
      As[k4 + 1][r] = v.y;
      As[k4 + 2][r] = v.z;
      As[k4 + 3][r] = v.w;
    }
    // B tile: 128 k x 64 cols
    for (int l = tid; l < 128 * 16; l += 256) {
      int k = l >> 4;
      int c4 = (l & 15) << 2;
      *(float4*)&Bs[k][c4] =
          *(const float4*)(BS + (size_t)(kt + k) * DD + col0 + c4);
    }
    __syncthreads();

#pragma unroll 8
    for (int k = 0; k < 128; ++k) {
      float4 a = *(const float4*)&As[k][ty * 4];
      float4 b = *(const float4*)&Bs[k][tx * 4];
      float av[4] = {a.x, a.y, a.z, a.w};
      float bv[4] = {b.x, b.y, b.z, b.w};
#pragma unroll
      for (int i = 0; i < 4; ++i)
#pragma unroll
        for (int j = 0; j < 4; ++j) acc[i][j] += av[i] * bv[j];
    }
    __syncthreads();
  }

  float4 bb = *(const float4*)(bias + col0 + tx * 4);
#pragma unroll
  for (int i = 0; i < 4; ++i) {
    int grow = row0 + ty * 4 + i;
    if (grow < NN) {
      float4 o;
      o.x = acc[i][0] + bb.x;
      o.y = acc[i][1] + bb.y;
      o.z = acc[i][2] + bb.z;
      o.w = acc[i][3] + bb.w;
      if (do_relu) {
        o.x = fmaxf(o.x, 0.f);
        o.y = fmaxf(o.y, 0.f);
        o.z = fmaxf(o.z, 0.f);
        o.w = fmaxf(o.w, 0.f);
      }
      *(float4*)(C + (size_t)grow * DD + col0 + tx * 4) = o;
    }
  }
}

// ---------------------------------------------------------------------------
extern "C" void kernel_launch(void* const* d_in, const int* in_sizes, int n_in,
                              void* d_out, int out_size, void* d_ws,
                              size_t ws_size, hipStream_t stream) {
  const float* x      = (const float*)d_in[0];
  const int*   eidx   = (const int*)d_in[1];
  const int*   etype  = (const int*)d_in[2];
  const float* basis1 = (const float*)d_in[3];
  const float* comp1  = (const float*)d_in[4];
  const float* root1  = (const float*)d_in[5];
  const float* bias1  = (const float*)d_in[6];
  const float* basis2 = (const float*)d_in[7];
  const float* comp2  = (const float*)d_in[8];
  const float* root2  = (const float*)d_in[9];
  const float* bias2  = (const float*)d_in[10];
  float* out = (float*)d_out;

  const int* src = eidx;
  const int* dst = eidx + NE;

  // workspace layout (4-byte units, all chunks multiple-of-4 elements)
  float* A    = (float*)d_ws;                 // [NN,640]  32.0M f
  float* h    = A + (size_t)NN * KTOT;        // [NN,128]   6.4M f
  float* BS1  = h + (size_t)NN * DD;          // [640,128]
  float* BS2  = BS1 + KTOT * DD;
  float* sinv = BS2 + KTOT * DD;              // [NE]
  int*   skey = (int*)(sinv + NE);            // [NE]
  int*   cnt  = skey + NE;                    // [NR]
  int*   deg  = cnt + NR;                     // [NN]
  int*   offs = deg + NN;                     // [NN]
  int*   curs = offs + NN;                    // [NN]
  int*   part = curs + NN;                    // [256]

  const int NB = (NN + 255) / 256;  // 196 scan blocks

  // ---- static graph structure (shared by both layers) ----
  hipMemsetAsync(cnt, 0, (NR + NN) * sizeof(int), stream);  // cnt + deg
  count_kernel<<<(NE + 255) / 256, 256, 0, stream>>>(dst, etype, cnt, deg);
  scan1_kernel<<<NB, 256, 0, stream>>>(deg, offs, part);
  scan2_kernel<<<1, 256, 0, stream>>>(part, NB);
  scan3_kernel<<<NB, 256, 0, stream>>>(offs, part, curs);
  sort_kernel<<<(NE + 255) / 256, 256, 0, stream>>>(src, dst, etype, cnt, curs,
                                                    skey, sinv);

  // ---- stacked weights: BS = [basis (512x128); root (128x128)] ----
  hipMemcpyAsync(BS1, basis1, (size_t)NBASIS * DD * DD * sizeof(float),
                 hipMemcpyDeviceToDevice, stream);
  hipMemcpyAsync(BS1 + (size_t)NBASIS * DD * DD, root1,
                 (size_t)DD * DD * sizeof(float), hipMemcpyDeviceToDevice,
                 stream);
  hipMemcpyAsync(BS2, basis2, (size_t)NBASIS * DD * DD * sizeof(float),
                 hipMemcpyDeviceToDevice, stream);
  hipMemcpyAsync(BS2 + (size_t)NBASIS * DD * DD, root2,
                 (size_t)DD * DD * sizeof(float), hipMemcpyDeviceToDevice,
                 stream);

  dim3 ggrid((NN + 63) / 64, DD / 64);  // 782 x 2
  int agg_blocks = (NN + 3) / 4;        // 12500

  // ---- layer 1 ----
  agg_kernel<<<agg_blocks, 256, 0, stream>>>(x, skey, sinv, comp1, offs, deg, A);
  gemm640_kernel<<<ggrid, 256, 0, stream>>>(A, BS1, bias1, h, 1);

  // ---- layer 2 ----
  agg_kernel<<<agg_blocks, 256, 0, stream>>>(h, skey, sinv, comp2, offs, deg, A);
  gemm640_kernel<<<ggrid, 256, 0, stream>>>(A, BS2, bias2, out, 0);
}

// Round 3
// 306.342 us; speedup vs baseline: 5.3837x; 2.0039x over previous
//
#include <hip/hip_runtime.h>

#define NN 50000
#define NE 600000
#define DD 128
#define RR 8
#define NBASIS 4
#define NR (NN * RR)
#define KTOT 640      // 4*128 (z bases) + 128 (self feat)
#define MPAD 50048    // 391 * 128

typedef float f32x4 __attribute__((ext_vector_type(4)));
typedef short bf16x8 __attribute__((ext_vector_type(8)));

static __device__ __forceinline__ unsigned short f2b(float f) {
  union { float f; unsigned u; } c; c.f = f;
  unsigned u = c.u + 0x7fffu + ((c.u >> 16) & 1u);  // RNE
  return (unsigned short)(u >> 16);
}
static __device__ __forceinline__ unsigned pack2(float lo, float hi) {
  return (unsigned)f2b(lo) | ((unsigned)f2b(hi) << 16);
}
static __device__ __forceinline__ float b2f_lo(unsigned v) {
  union { unsigned u; float f; } c; c.u = v << 16; return c.f;
}
static __device__ __forceinline__ float b2f_hi(unsigned v) {
  union { unsigned u; float f; } c; c.u = v & 0xffff0000u; return c.f;
}

// ---------------------------------------------------------------------------
__global__ __launch_bounds__(256) void count_kernel(
    const int* __restrict__ dst, const int* __restrict__ et,
    int* __restrict__ cnt, int* __restrict__ deg) {
  int e = blockIdx.x * 256 + threadIdx.x;
  if (e < NE) {
    int d = dst[e];
    atomicAdd(&cnt[d * RR + et[e]], 1);
    atomicAdd(&deg[d], 1);
  }
}

__global__ __launch_bounds__(256) void scan1_kernel(
    const int* __restrict__ deg, int* __restrict__ offs,
    int* __restrict__ partials) {
  __shared__ int s[256];
  int t = threadIdx.x;
  int i = blockIdx.x * 256 + t;
  int v = (i < NN) ? deg[i] : 0;
  s[t] = v;
  __syncthreads();
  for (int off = 1; off < 256; off <<= 1) {
    int add = (t >= off) ? s[t - off] : 0;
    __syncthreads();
    s[t] += add;
    __syncthreads();
  }
  if (i < NN) offs[i] = s[t] - v;
  if (t == 255) partials[blockIdx.x] = s[255];
}

__global__ __launch_bounds__(256) void scan2_kernel(
    int* __restrict__ partials, int nb) {
  __shared__ int s[256];
  int t = threadIdx.x;
  int v = (t < nb) ? partials[t] : 0;
  s[t] = v;
  __syncthreads();
  for (int off = 1; off < 256; off <<= 1) {
    int add = (t >= off) ? s[t - off] : 0;
    __syncthreads();
    s[t] += add;
    __syncthreads();
  }
  if (t < nb) partials[t] = s[t] - v;
}

__global__ __launch_bounds__(256) void scan3_kernel(
    int* __restrict__ offs, const int* __restrict__ partials,
    int* __restrict__ cursor) {
  int i = blockIdx.x * 256 + threadIdx.x;
  if (i < NN) {
    int o = offs[i] + partials[blockIdx.x];
    offs[i] = o;
    cursor[i] = o;
  }
}

__global__ __launch_bounds__(256) void sort_kernel(
    const int* __restrict__ src, const int* __restrict__ dst,
    const int* __restrict__ et, const int* __restrict__ cnt,
    int* __restrict__ cursor, int* __restrict__ skey,
    float* __restrict__ sinv) {
  int e = blockIdx.x * 256 + threadIdx.x;
  if (e >= NE) return;
  int d = dst[e];
  int t = et[e];
  int p = atomicAdd(&cursor[d], 1);
  skey[p] = src[e] | (t << 28);
  sinv[p] = 1.0f / (float)cnt[d * RR + t];
}

// ---------------------------------------------------------------------------
__global__ __launch_bounds__(256) void tobf16_kernel(
    const float* __restrict__ in, unsigned* __restrict__ outb, int npairs) {
  int i = blockIdx.x * 256 + threadIdx.x;
  if (i < npairs) {
    float2 v = ((const float2*)in)[i];
    outb[i] = pack2(v.x, v.y);
  }
}

// BT[c][k] (bf16, [128][640]): k<512 -> basis[k>>7][k&127][c], else root[k-512][c]
__global__ __launch_bounds__(256) void btbuild_kernel(
    const float* __restrict__ basis, const float* __restrict__ root,
    unsigned short* __restrict__ BT) {
  int idx = blockIdx.x * 256 + threadIdx.x;
  if (idx >= DD * KTOT) return;
  int c = idx / KTOT;
  int k = idx - c * KTOT;
  float v = (k < 512) ? basis[(size_t)((k >> 7) * DD + (k & 127)) * DD + c]
                      : root[(size_t)(k - 512) * DD + c];
  BT[idx] = f2b(v);
}

// ---------------------------------------------------------------------------
// One wave per dst node. z[b] = sum_edges (comp[t,b]/cnt) * feat_src (bf16 in,
// f32 accum).  A row (bf16): cols [0,512)=z, [512,640)=self feat.
__global__ __launch_bounds__(256) void agg_kernel(
    const unsigned* __restrict__ featb,  // [NN][64] packed bf16 pairs
    const int* __restrict__ skey, const float* __restrict__ sinv,
    const float* __restrict__ comp, const int* __restrict__ offs,
    const int* __restrict__ deg, unsigned* __restrict__ Ab) {  // [MPAD][320]
  __shared__ float scomp[RR * NBASIS];
  if (threadIdx.x < RR * NBASIS) scomp[threadIdx.x] = comp[threadIdx.x];
  __syncthreads();

  int node = blockIdx.x * 4 + (threadIdx.x >> 6);
  if (node >= NN) return;
  int lane = threadIdx.x & 63;

  float z00 = 0, z01 = 0, z10 = 0, z11 = 0;
  float z20 = 0, z21 = 0, z30 = 0, z31 = 0;

  int beg = offs[node];
  int end = beg + deg[node];
  for (int i = beg; i < end; ++i) {
    int key = skey[i];
    int s = key & 0x0FFFFFFF;
    int t = key >> 28;
    float iv = sinv[i];
    unsigned v = featb[(size_t)s * 64 + lane];
    float e0 = b2f_lo(v), e1 = b2f_hi(v);
    float c0 = iv * scomp[t * NBASIS + 0];
    float c1 = iv * scomp[t * NBASIS + 1];
    float c2 = iv * scomp[t * NBASIS + 2];
    float c3 = iv * scomp[t * NBASIS + 3];
    z00 += c0 * e0; z01 += c0 * e1;
    z10 += c1 * e0; z11 += c1 * e1;
    z20 += c2 * e0; z21 += c2 * e1;
    z30 += c3 * e0; z31 += c3 * e1;
  }

  unsigned* Arow = Ab + (size_t)node * 320;
  Arow[0 * 64 + lane] = pack2(z00, z01);
  Arow[1 * 64 + lane] = pack2(z10, z11);
  Arow[2 * 64 + lane] = pack2(z20, z21);
  Arow[3 * 64 + lane] = pack2(z30, z31);
  Arow[4 * 64 + lane] = featb[(size_t)node * 64 + lane];
}

// ---------------------------------------------------------------------------
// C[M,128] = A[M,640]bf16 @ BT^T (BT is [128 cols][640 k] bf16), +bias.
// 128x128 tile, BK=64, 4 waves 2x2, mfma_f32_16x16x32_bf16, 4x4 frags/wave.
template <int OUT_BF16>
__global__ __launch_bounds__(256) void gemm_mfma(
    const unsigned short* __restrict__ Ab, const unsigned short* __restrict__ BT,
    const float* __restrict__ bias, void* __restrict__ Cout) {
  __shared__ unsigned short As[128][64];  // [row][k]
  __shared__ unsigned short Bs[128][64];  // [col][k]

  int tid = threadIdx.x;
  int row0 = blockIdx.x * 128;
  int lane = tid & 63;
  int wid = tid >> 6;
  int wr = (wid >> 1) * 64;
  int wc = (wid & 1) * 64;

  f32x4 acc[4][4] = {};

  for (int kt = 0; kt < KTOT; kt += 64) {
#pragma unroll
    for (int i = 0; i < 4; ++i) {
      int off = i * 256 + tid;      // 16B chunk index, 0..1023
      int r = off >> 3;             // row (As) / col (Bs)
      int ke = (off & 7) << 3;      // bf16 element offset in [0,64)
      *(uint4*)((unsigned short*)As + (size_t)off * 8) =
          *(const uint4*)(Ab + (size_t)(row0 + r) * KTOT + kt + ke);
      *(uint4*)((unsigned short*)Bs + (size_t)off * 8) =
          *(const uint4*)(BT + (size_t)r * KTOT + kt + ke);
    }
    __syncthreads();

#pragma unroll
    for (int kk = 0; kk < 2; ++kk) {
      int ko = kk * 32 + ((lane >> 4) << 3);
      bf16x8 a[4], b[4];
#pragma unroll
      for (int m = 0; m < 4; ++m)
        a[m] = *(const bf16x8*)&As[wr + m * 16 + (lane & 15)][ko];
#pragma unroll
      for (int n = 0; n < 4; ++n)
        b[n] = *(const bf16x8*)&Bs[wc + n * 16 + (lane & 15)][ko];
#pragma unroll
      for (int m = 0; m < 4; ++m)
#pragma unroll
        for (int n = 0; n < 4; ++n)
          acc[m][n] = __builtin_amdgcn_mfma_f32_16x16x32_bf16(
              a[m], b[n], acc[m][n], 0, 0, 0);
    }
    __syncthreads();
  }

#pragma unroll
  for (int n = 0; n < 4; ++n) {
    int col = wc + n * 16 + (lane & 15);
    float bb = bias[col];
#pragma unroll
    for (int m = 0; m < 4; ++m) {
      f32x4 v = acc[m][n];
#pragma unroll
      for (int j = 0; j < 4; ++j) {
        int row = row0 + wr + m * 16 + ((lane >> 4) << 2) + j;
        if (row < NN) {
          float o = v[j] + bb;
          if (OUT_BF16) {
            o = fmaxf(o, 0.f);
            ((unsigned short*)Cout)[(size_t)row * DD + col] = f2b(o);
          } else {
            ((float*)Cout)[(size_t)row * DD + col] = o;
          }
        }
      }
    }
  }
}

// ---------------------------------------------------------------------------
extern "C" void kernel_launch(void* const* d_in, const int* in_sizes, int n_in,
                              void* d_out, int out_size, void* d_ws,
                              size_t ws_size, hipStream_t stream) {
  const float* x      = (const float*)d_in[0];
  const int*   eidx   = (const int*)d_in[1];
  const int*   etype  = (const int*)d_in[2];
  const float* basis1 = (const float*)d_in[3];
  const float* comp1  = (const float*)d_in[4];
  const float* root1  = (const float*)d_in[5];
  const float* bias1  = (const float*)d_in[6];
  const float* basis2 = (const float*)d_in[7];
  const float* comp2  = (const float*)d_in[8];
  const float* root2  = (const float*)d_in[9];
  const float* bias2  = (const float*)d_in[10];
  float* out = (float*)d_out;

  const int* src = eidx;
  const int* dst = eidx + NE;

  // workspace layout
  unsigned short* Ab  = (unsigned short*)d_ws;         // [MPAD][640] bf16
  unsigned short* hb  = Ab + (size_t)MPAD * KTOT;      // [NN][128] bf16
  unsigned short* xb  = hb + (size_t)NN * DD;          // [NN][128] bf16
  unsigned short* BT1 = xb + (size_t)NN * DD;          // [128][640] bf16
  unsigned short* BT2 = BT1 + (size_t)DD * KTOT;
  float* sinv = (float*)(BT2 + (size_t)DD * KTOT);     // [NE]
  int*   skey = (int*)(sinv + NE);                     // [NE]
  int*   cnt  = skey + NE;                             // [NR]
  int*   deg  = cnt + NR;                              // [NN]
  int*   offs = deg + NN;                              // [NN]
  int*   curs = offs + NN;                             // [NN]
  int*   part = curs + NN;                             // [256]

  const int NB = (NN + 255) / 256;  // 196

  // ---- static graph structure ----
  hipMemsetAsync(cnt, 0, (size_t)(NR + NN) * sizeof(int), stream);
  count_kernel<<<(NE + 255) / 256, 256, 0, stream>>>(dst, etype, cnt, deg);
  scan1_kernel<<<NB, 256, 0, stream>>>(deg, offs, part);
  scan2_kernel<<<1, 256, 0, stream>>>(part, NB);
  scan3_kernel<<<NB, 256, 0, stream>>>(offs, part, curs);
  sort_kernel<<<(NE + 255) / 256, 256, 0, stream>>>(src, dst, etype, cnt, curs,
                                                    skey, sinv);

  // ---- bf16 conversions ----
  tobf16_kernel<<<(NN * DD / 2 + 255) / 256, 256, 0, stream>>>(
      x, (unsigned*)xb, NN * DD / 2);
  btbuild_kernel<<<(DD * KTOT + 255) / 256, 256, 0, stream>>>(basis1, root1, BT1);
  btbuild_kernel<<<(DD * KTOT + 255) / 256, 256, 0, stream>>>(basis2, root2, BT2);

  int agg_blocks = (NN + 3) / 4;          // 12500
  int gemm_blocks = MPAD / 128;           // 391

  // ---- layer 1 ----
  agg_kernel<<<agg_blocks, 256, 0, stream>>>((const unsigned*)xb, skey, sinv,
                                             comp1, offs, deg, (unsigned*)Ab);
  gemm_mfma<1><<<gemm_blocks, 256, 0, stream>>>(Ab, BT1, bias1, hb);

  // ---- layer 2 ----
  agg_kernel<<<agg_blocks, 256, 0, stream>>>((const unsigned*)hb, skey, sinv,
                                             comp2, offs, deg, (unsigned*)Ab);
  gemm_mfma<0><<<gemm_blocks, 256, 0, stream>>>(Ab, BT2, bias2, out);
}

// Round 4
// 258.713 us; speedup vs baseline: 6.3748x; 1.1841x over previous
//
#include <hip/hip_runtime.h>

#define NN 50000
#define NE 600000
#define DD 128
#define RR 8
#define NBASIS 4
#define NR (NN * RR)
#define KTOT 640      // 4*128 (z bases) + 128 (self feat)
#define MPAD 50048    // 391 * 128

typedef float f32x4 __attribute__((ext_vector_type(4)));
typedef short bf16x8 __attribute__((ext_vector_type(8)));

static __device__ __forceinline__ unsigned short f2b(float f) {
  union { float f; unsigned u; } c; c.f = f;
  unsigned u = c.u + 0x7fffu + ((c.u >> 16) & 1u);  // RNE
  return (unsigned short)(u >> 16);
}
static __device__ __forceinline__ unsigned pack2(float lo, float hi) {
  return (unsigned)f2b(lo) | ((unsigned)f2b(hi) << 16);
}
static __device__ __forceinline__ float b2f_lo(unsigned v) {
  union { unsigned u; float f; } c; c.u = v << 16; return c.f;
}
static __device__ __forceinline__ float b2f_hi(unsigned v) {
  union { unsigned u; float f; } c; c.u = v & 0xffff0000u; return c.f;
}

// ---------------------------------------------------------------------------
__global__ __launch_bounds__(256) void count_kernel(
    const int* __restrict__ dst, const int* __restrict__ et,
    int* __restrict__ cnt) {
  int e = blockIdx.x * 256 + threadIdx.x;
  if (e < NE) atomicAdd(&cnt[dst[e] * RR + et[e]], 1);
}

// scan1 also derives deg[i] = sum_t cnt[i*8+t]
__global__ __launch_bounds__(256) void scan1_kernel(
    const int* __restrict__ cnt, int* __restrict__ deg,
    int* __restrict__ offs, int* __restrict__ partials) {
  __shared__ int s[256];
  int t = threadIdx.x;
  int i = blockIdx.x * 256 + t;
  int v = 0;
  if (i < NN) {
    const int4* c4 = (const int4*)cnt;
    int4 a = c4[i * 2];
    int4 b = c4[i * 2 + 1];
    v = a.x + a.y + a.z + a.w + b.x + b.y + b.z + b.w;
    deg[i] = v;
  }
  s[t] = v;
  __syncthreads();
  for (int off = 1; off < 256; off <<= 1) {
    int add = (t >= off) ? s[t - off] : 0;
    __syncthreads();
    s[t] += add;
    __syncthreads();
  }
  if (i < NN) offs[i] = s[t] - v;
  if (t == 255) partials[blockIdx.x] = s[255];
}

__global__ __launch_bounds__(256) void scan2_kernel(
    int* __restrict__ partials, int nb) {
  __shared__ int s[256];
  int t = threadIdx.x;
  int v = (t < nb) ? partials[t] : 0;
  s[t] = v;
  __syncthreads();
  for (int off = 1; off < 256; off <<= 1) {
    int add = (t >= off) ? s[t - off] : 0;
    __syncthreads();
    s[t] += add;
    __syncthreads();
  }
  if (t < nb) partials[t] = s[t] - v;
}

__global__ __launch_bounds__(256) void scan3_kernel(
    int* __restrict__ offs, const int* __restrict__ partials,
    int* __restrict__ cursor) {
  int i = blockIdx.x * 256 + threadIdx.x;
  if (i < NN) {
    int o = offs[i] + partials[blockIdx.x];
    offs[i] = o;
    cursor[i] = o;
  }
}

__global__ __launch_bounds__(256) void sort_kernel(
    const int* __restrict__ src, const int* __restrict__ dst,
    const int* __restrict__ et, const int* __restrict__ cnt,
    int* __restrict__ cursor, int* __restrict__ skey,
    float* __restrict__ sinv) {
  int e = blockIdx.x * 256 + threadIdx.x;
  if (e >= NE) return;
  int d = dst[e];
  int t = et[e];
  int p = atomicAdd(&cursor[d], 1);
  skey[p] = src[e] | (t << 28);
  sinv[p] = 1.0f / (float)cnt[d * RR + t];
}

// Per-edge folded coefficients c_b = (1/cnt) * comp[t][b], both layers.
__global__ __launch_bounds__(256) void scv_kernel(
    const int* __restrict__ skey, const float* __restrict__ sinv,
    const float* __restrict__ comp1, const float* __restrict__ comp2,
    float4* __restrict__ scv1, float4* __restrict__ scv2) {
  int e = blockIdx.x * 256 + threadIdx.x;
  if (e >= NE) return;
  int t = ((unsigned)skey[e]) >> 28;
  float iv = sinv[e];
  scv1[e] = make_float4(iv * comp1[t * NBASIS + 0], iv * comp1[t * NBASIS + 1],
                        iv * comp1[t * NBASIS + 2], iv * comp1[t * NBASIS + 3]);
  scv2[e] = make_float4(iv * comp2[t * NBASIS + 0], iv * comp2[t * NBASIS + 1],
                        iv * comp2[t * NBASIS + 2], iv * comp2[t * NBASIS + 3]);
}

// ---------------------------------------------------------------------------
__global__ __launch_bounds__(256) void tobf16_kernel(
    const float* __restrict__ in, unsigned* __restrict__ outb, int npairs) {
  int i = blockIdx.x * 256 + threadIdx.x;
  if (i < npairs) {
    float2 v = ((const float2*)in)[i];
    outb[i] = pack2(v.x, v.y);
  }
}

// BT[c][k] (bf16, [128][640]): k<512 -> basis[k>>7][k&127][c], else root[k-512][c]
__global__ __launch_bounds__(256) void btbuild_kernel(
    const float* __restrict__ basis, const float* __restrict__ root,
    unsigned short* __restrict__ BT) {
  int idx = blockIdx.x * 256 + threadIdx.x;
  if (idx >= DD * KTOT) return;
  int c = idx / KTOT;
  int k = idx - c * KTOT;
  float v = (k < 512) ? basis[(size_t)((k >> 7) * DD + (k & 127)) * DD + c]
                      : root[(size_t)(k - 512) * DD + c];
  BT[idx] = f2b(v);
}

// ---------------------------------------------------------------------------
// One wave per dst node, 4x16-lane edge groups (4 gathers in flight).
// Group g streams edges beg+g, beg+g+4, ...; lane q owns feature bytes
// [q*16, q*16+16) of the 256B bf16 row.  Cross-group combine via shfl_xor.
__global__ __launch_bounds__(256) void agg_kernel(
    const uint4* __restrict__ featb4,   // [NN][16] (bf16 rows as uint4)
    const int* __restrict__ skey, const float4* __restrict__ scv,
    const int* __restrict__ offs, const int* __restrict__ deg,
    uint4* __restrict__ Ab4) {          // [MPAD][80]
  int node = blockIdx.x * 4 + (threadIdx.x >> 6);
  if (node >= NN) return;
  int lane = threadIdx.x & 63;
  int g = lane >> 4;
  int q = lane & 15;

  float a0[8] = {}, a1[8] = {}, a2[8] = {}, a3[8] = {};

  int beg = offs[node];
  int dg = deg[node];
  for (int i = g; i < dg; i += 4) {
    int key = skey[beg + i];
    int s = key & 0x0FFFFFFF;
    float4 c = scv[beg + i];
    uint4 v = featb4[(size_t)s * 16 + q];
    float e[8];
    e[0] = b2f_lo(v.x); e[1] = b2f_hi(v.x);
    e[2] = b2f_lo(v.y); e[3] = b2f_hi(v.y);
    e[4] = b2f_lo(v.z); e[5] = b2f_hi(v.z);
    e[6] = b2f_lo(v.w); e[7] = b2f_hi(v.w);
#pragma unroll
    for (int j = 0; j < 8; ++j) {
      a0[j] += c.x * e[j];
      a1[j] += c.y * e[j];
      a2[j] += c.z * e[j];
      a3[j] += c.w * e[j];
    }
  }

  // combine the 4 edge-group partials (lanes differing in bits 4,5)
#pragma unroll
  for (int j = 0; j < 8; ++j) {
    a0[j] += __shfl_xor(a0[j], 16); a0[j] += __shfl_xor(a0[j], 32);
    a1[j] += __shfl_xor(a1[j], 16); a1[j] += __shfl_xor(a1[j], 32);
    a2[j] += __shfl_xor(a2[j], 16); a2[j] += __shfl_xor(a2[j], 32);
    a3[j] += __shfl_xor(a3[j], 16); a3[j] += __shfl_xor(a3[j], 32);
  }

  uint4* row = Ab4 + (size_t)node * 80;
  uint4 w;
  if (g == 0) {
    w.x = pack2(a0[0], a0[1]); w.y = pack2(a0[2], a0[3]);
    w.z = pack2(a0[4], a0[5]); w.w = pack2(a0[6], a0[7]);
  } else if (g == 1) {
    w.x = pack2(a1[0], a1[1]); w.y = pack2(a1[2], a1[3]);
    w.z = pack2(a1[4], a1[5]); w.w = pack2(a1[6], a1[7]);
  } else if (g == 2) {
    w.x = pack2(a2[0], a2[1]); w.y = pack2(a2[2], a2[3]);
    w.z = pack2(a2[4], a2[5]); w.w = pack2(a2[6], a2[7]);
  } else {
    w.x = pack2(a3[0], a3[1]); w.y = pack2(a3[2], a3[3]);
    w.z = pack2(a3[4], a3[5]); w.w = pack2(a3[6], a3[7]);
  }
  row[g * 16 + q] = w;                       // basis g, cols [g*128 + q*8 ...)
  if (g == 0) row[64 + q] = featb4[(size_t)node * 16 + q];  // self feat
}

// ---------------------------------------------------------------------------
// C[M,128] = A[M,640]bf16 @ BT^T (BT is [128 cols][640 k] bf16), +bias.
// 128x128 tile, BK=64, 4 waves 2x2, mfma_f32_16x16x32_bf16, 4x4 frags/wave.
template <int OUT_BF16>
__global__ __launch_bounds__(256) void gemm_mfma(
    const unsigned short* __restrict__ Ab, const unsigned short* __restrict__ BT,
    const float* __restrict__ bias, void* __restrict__ Cout) {
  __shared__ unsigned short As[128][64];  // [row][k]
  __shared__ unsigned short Bs[128][64];  // [col][k]

  int tid = threadIdx.x;
  int row0 = blockIdx.x * 128;
  int lane = tid & 63;
  int wid = tid >> 6;
  int wr = (wid >> 1) * 64;
  int wc = (wid & 1) * 64;

  f32x4 acc[4][4] = {};

  for (int kt = 0; kt < KTOT; kt += 64) {
#pragma unroll
    for (int i = 0; i < 4; ++i) {
      int off = i * 256 + tid;      // 16B chunk index, 0..1023
      int r = off >> 3;             // row (As) / col (Bs)
      int ke = (off & 7) << 3;      // bf16 element offset in [0,64)
      *(uint4*)((unsigned short*)As + (size_t)off * 8) =
          *(const uint4*)(Ab + (size_t)(row0 + r) * KTOT + kt + ke);
      *(uint4*)((unsigned short*)Bs + (size_t)off * 8) =
          *(const uint4*)(BT + (size_t)r * KTOT + kt + ke);
    }
    __syncthreads();

#pragma unroll
    for (int kk = 0; kk < 2; ++kk) {
      int ko = kk * 32 + ((lane >> 4) << 3);
      bf16x8 a[4], b[4];
#pragma unroll
      for (int m = 0; m < 4; ++m)
        a[m] = *(const bf16x8*)&As[wr + m * 16 + (lane & 15)][ko];
#pragma unroll
      for (int n = 0; n < 4; ++n)
        b[n] = *(const bf16x8*)&Bs[wc + n * 16 + (lane & 15)][ko];
#pragma unroll
      for (int m = 0; m < 4; ++m)
#pragma unroll
        for (int n = 0; n < 4; ++n)
          acc[m][n] = __builtin_amdgcn_mfma_f32_16x16x32_bf16(
              a[m], b[n], acc[m][n], 0, 0, 0);
    }
    __syncthreads();
  }

#pragma unroll
  for (int n = 0; n < 4; ++n) {
    int col = wc + n * 16 + (lane & 15);
    float bb = bias[col];
#pragma unroll
    for (int m = 0; m < 4; ++m) {
      f32x4 v = acc[m][n];
#pragma unroll
      for (int j = 0; j < 4; ++j) {
        int row = row0 + wr + m * 16 + ((lane >> 4) << 2) + j;
        if (row < NN) {
          float o = v[j] + bb;
          if (OUT_BF16) {
            o = fmaxf(o, 0.f);
            ((unsigned short*)Cout)[(size_t)row * DD + col] = f2b(o);
          } else {
            ((float*)Cout)[(size_t)row * DD + col] = o;
          }
        }
      }
    }
  }
}

// ---------------------------------------------------------------------------
extern "C" void kernel_launch(void* const* d_in, const int* in_sizes, int n_in,
                              void* d_out, int out_size, void* d_ws,
                              size_t ws_size, hipStream_t stream) {
  const float* x      = (const float*)d_in[0];
  const int*   eidx   = (const int*)d_in[1];
  const int*   etype  = (const int*)d_in[2];
  const float* basis1 = (const float*)d_in[3];
  const float* comp1  = (const float*)d_in[4];
  const float* root1  = (const float*)d_in[5];
  const float* bias1  = (const float*)d_in[6];
  const float* basis2 = (const float*)d_in[7];
  const float* comp2  = (const float*)d_in[8];
  const float* root2  = (const float*)d_in[9];
  const float* bias2  = (const float*)d_in[10];
  float* out = (float*)d_out;

  const int* src = eidx;
  const int* dst = eidx + NE;

  // workspace layout (16B-aligned chunks first)
  unsigned short* Ab  = (unsigned short*)d_ws;         // [MPAD][640] bf16
  unsigned short* hb  = Ab + (size_t)MPAD * KTOT;      // [NN][128] bf16
  unsigned short* xb  = hb + (size_t)NN * DD;          // [NN][128] bf16
  unsigned short* BT1 = xb + (size_t)NN * DD;          // [128][640] bf16
  unsigned short* BT2 = BT1 + (size_t)DD * KTOT;
  float4* scv1 = (float4*)(BT2 + (size_t)DD * KTOT);   // [NE]
  float4* scv2 = scv1 + NE;                            // [NE]
  float* sinv = (float*)(scv2 + NE);                   // [NE]
  int*   skey = (int*)(sinv + NE);                     // [NE]
  int*   cnt  = skey + NE;                             // [NR]
  int*   deg  = cnt + NR;                              // [NN]
  int*   offs = deg + NN;                              // [NN]
  int*   curs = offs + NN;                             // [NN]
  int*   part = curs + NN;                             // [256]

  const int NB = (NN + 255) / 256;  // 196
  const int EB = (NE + 255) / 256;

  // ---- static graph structure ----
  hipMemsetAsync(cnt, 0, (size_t)NR * sizeof(int), stream);
  count_kernel<<<EB, 256, 0, stream>>>(dst, etype, cnt);
  scan1_kernel<<<NB, 256, 0, stream>>>(cnt, deg, offs, part);
  scan2_kernel<<<1, 256, 0, stream>>>(part, NB);
  scan3_kernel<<<NB, 256, 0, stream>>>(offs, part, curs);
  sort_kernel<<<EB, 256, 0, stream>>>(src, dst, etype, cnt, curs, skey, sinv);
  scv_kernel<<<EB, 256, 0, stream>>>(skey, sinv, comp1, comp2, scv1, scv2);

  // ---- bf16 conversions ----
  tobf16_kernel<<<(NN * DD / 2 + 255) / 256, 256, 0, stream>>>(
      x, (unsigned*)xb, NN * DD / 2);
  btbuild_kernel<<<(DD * KTOT + 255) / 256, 256, 0, stream>>>(basis1, root1, BT1);
  btbuild_kernel<<<(DD * KTOT + 255) / 256, 256, 0, stream>>>(basis2, root2, BT2);

  int agg_blocks = (NN + 3) / 4;   // 12500
  int gemm_blocks = MPAD / 128;    // 391

  // ---- layer 1 ----
  agg_kernel<<<agg_blocks, 256, 0, stream>>>((const uint4*)xb, skey, scv1,
                                             offs, deg, (uint4*)Ab);
  gemm_mfma<1><<<gemm_blocks, 256, 0, stream>>>(Ab, BT1, bias1, hb);

  // ---- layer 2 ----
  agg_kernel<<<agg_blocks, 256, 0, stream>>>((const uint4*)hb, skey, scv2,
                                             offs, deg, (uint4*)Ab);
  gemm_mfma<0><<<gemm_blocks, 256, 0, stream>>>(Ab, BT2, bias2, out);
}